// Round 12
// baseline (266.257 us; speedup 1.0000x reference)
//
#include <hip/hip_runtime.h>
#include <stdint.h>

#define B_ROWS 8192
#define I_DIM  1024
#define N_DIM  1024
#define NDEG   9                  // D+1 (d = 0..8)
#define K_DIM  (I_DIM * (NDEG-1)) // 8192; k = i*8 + (d-1), d = 1..8 (d=0 folded into bias)

#define BM 256
#define BN 128
#define BK 64
#define NT (K_DIM / BK)           // 128 K-tiles; tile kt covers i in [kt*8, kt*8+8)

typedef __attribute__((ext_vector_type(8)))  short short8;
typedef __attribute__((ext_vector_type(16))) float f32x16;

__device__ __forceinline__ unsigned short f2bf(float f) {
  union { float f; uint32_t u; } v; v.f = f;
  uint32_t u = v.u;
  u += 0x7FFFu + ((u >> 16) & 1u);   // round-to-nearest-even
  return (unsigned short)(u >> 16);
}

__device__ __forceinline__ float bf2f(unsigned short h) {
  union { uint32_t u; float f; } v; v.u = ((uint32_t)h) << 16;
  return v.f;
}

// packed f32->bf16 (RTNE), 1 instr for 2 values; no builtin on gfx950, asm only
__device__ __forceinline__ uint32_t pk_bf16(float lo, float hi) {
  uint32_t r;
  asm("v_cvt_pk_bf16_f32 %0, %1, %2" : "=v"(r) : "v"(lo), "v"(hi));
  return r;
}

// fast tanh: 1 - 2/(e^{2x}+1); exact limits at +-inf, err ~1e-7 << bf16 quantization
__device__ __forceinline__ float fast_tanh(float x) {
  float e = __expf(2.0f * x);
  return 1.0f - __fdividef(2.0f, e + 1.0f);
}

// ---------------- repack: C[i,o,d] fp32 -> Bt2 = per-(nt,kt) fragment-major LDS image ----
// Bt2 layout (shorts): nt*1048576 + kt*8192 + (gb*8 + c)*256 + r31*8 + (d-1)
//   where o = nt*128 + gb*32 + r31, i = kt*8 + c. Each (nt,kt) slab of 16 KB is the EXACT
//   B-LDS tile image -> gemm stages it with 4 contiguous linear global_load_lds per lane.
// bias[o] += sum_i C[i,o,0].
__global__ __launch_bounds__(256) void repack_kernel(const float* __restrict__ cf,
                                                     unsigned short* __restrict__ Bt2,
                                                     float* __restrict__ bias) {
  __shared__ unsigned short L[32][584];   // [i_local][o_local*9+d], padded
  const int i0  = blockIdx.x * 32;
  const int o0  = blockIdx.y * 64;
  const int tid = threadIdx.x;

  #pragma unroll
  for (int j = 0; j < 18; ++j) {               // 18*256 = 4608 float4 = 32*576 floats
    const int f4  = j * 256 + tid;
    const int il  = f4 / 144;
    const int odq = f4 % 144;
    const float4 v = *reinterpret_cast<const float4*>(
        cf + ((size_t)(i0 + il) * N_DIM + o0) * NDEG + (size_t)odq * 4);
    ushort4 w;
    w.x = f2bf(v.x); w.y = f2bf(v.y); w.z = f2bf(v.z); w.w = f2bf(v.w);
    *reinterpret_cast<ushort4*>(&L[il][odq * 4]) = w;
  }
  __syncthreads();

  // one (o, i-octet) per thread: 8 x uint4 (8 d-values each), fragment-major addressing
  const int o_rel = tid >> 2;     // 0..63
  const int ci    = tid & 3;      // 0..3
  const int o     = o0 + o_rel;
  const int ntb   = o >> 7;
  const int gb    = (o & 127) >> 5;
  const int r31   = o & 31;
  const int kti   = (i0 >> 3) + ci;
  const size_t base = (size_t)ntb * 1048576 + (size_t)kti * 8192 + (size_t)r31 * 8;
  #pragma unroll
  for (int p = 0; p < 8; ++p) {   // i = i0 + ci*8 + p -> chunk c = p
    const int il = ci * 8 + p;
    uint4 u;
    u.x = (uint32_t)L[il][o_rel*9 + 1] | ((uint32_t)L[il][o_rel*9 + 2] << 16);
    u.y = (uint32_t)L[il][o_rel*9 + 3] | ((uint32_t)L[il][o_rel*9 + 4] << 16);
    u.z = (uint32_t)L[il][o_rel*9 + 5] | ((uint32_t)L[il][o_rel*9 + 6] << 16);
    u.w = (uint32_t)L[il][o_rel*9 + 7] | ((uint32_t)L[il][o_rel*9 + 8] << 16);
    *reinterpret_cast<uint4*>(Bt2 + base + (size_t)(gb * 8 + p) * 256) = u;
  }
  if (tid < 64) {
    float s = 0.f;
    #pragma unroll
    for (int il = 0; il < 32; ++il) s += bf2f(L[il][tid * 9]);
    atomicAdd(&bias[o0 + tid], s);
  }
}

// ---------------- fused basis+GEMM, producer/consumer wave specialization ----------------
// R4 vs R7/R11 proved VALU adds ~1:1 to the wall when it lives in the consumer waves'
// instruction stream. This kernel: 768 threads = 8 CONSUMER waves (pure ds_read+MFMA,
// zero VMEM, zero basis VALU) + 4 PRODUCER waves (basis VALU + LDS writes + B-DMA +
// x-loads). Producer work overlaps consumer LDS/MFMA by construction (different waves).
// LDS is FRAGMENT-MAJOR for both A and B (32-lane x 16B blocks): consumer reads are
// uniform-base + l31*16 (0 conflicts); producer basis writes (lane=row, slot=chunk) are
// bank-sequential (0 conflicts); B-DMA is linear+contiguous from the Bt2 image (0
// conflicts, fully coalesced). Double-buffered 96 KB; one barrier/tile; producer-only
// counted vmcnt(2) (x prefetch rides across the barrier).
__global__ __launch_bounds__(768, 3) void gemm_kernel(const float* __restrict__ x,
                                                      const unsigned short* __restrict__ Bt2,
                                                      const float* __restrict__ bias,
                                                      float* __restrict__ C) {
  extern __shared__ unsigned short sm[];   // A: [2][16384] sh @0 ; B: [2][8192] sh @32768
  const int tid  = threadIdx.x;
  const int wave = tid >> 6;        // 0..11

  // bijective XCD swizzle: 8 n-blocks of one m-tile share bid%8 -> same XCD L2 (x reuse);
  // Bt2 (16.8 MB total) is L3-resident.
  const int bid = blockIdx.x;
  const int mt  = (bid & 7) + 8 * (bid >> 6);
  const int nt  = (bid >> 3) & 7;
  const int m0  = mt * BM;
  const int n0  = nt * BN;

  if (wave < 8) {
    // ================= CONSUMER: 8 waves, 2x2 x mfma_32x32x16 each =================
    const int lane = tid & 63;
    const int l31  = lane & 31;
    const int half = lane >> 5;
    const int wm   = wave >> 1;       // 0..3
    const int wn   = wave & 1;        // 0..1

    // fragment-major offsets (shorts): block (g*8+c)*256 + l31*8; chunk c = ks*2+half
    const int aoff0 = ((wm * 2 + 0) * 8 + half) * 256 + l31 * 8;
    const int aoff1 = ((wm * 2 + 1) * 8 + half) * 256 + l31 * 8;
    const int boff0 = ((wn * 2 + 0) * 8 + half) * 256 + l31 * 8;
    const int boff1 = ((wn * 2 + 1) * 8 + half) * 256 + l31 * 8;

    f32x16 acc[2][2];
    #pragma unroll
    for (int a = 0; a < 2; ++a)
      #pragma unroll
      for (int b = 0; b < 2; ++b)
        #pragma unroll
        for (int r = 0; r < 16; ++r)
          acc[a][b][r] = 0.f;

    short8 av[2][4], bv[2][4];

#define READ4(As_, Bs_, ks) {                                                                \
    av[0][ks] = *reinterpret_cast<const short8*>(&(As_)[aoff0 + (ks) * 512]);                \
    av[1][ks] = *reinterpret_cast<const short8*>(&(As_)[aoff1 + (ks) * 512]);                \
    bv[0][ks] = *reinterpret_cast<const short8*>(&(Bs_)[boff0 + (ks) * 512]);                \
    bv[1][ks] = *reinterpret_cast<const short8*>(&(Bs_)[boff1 + (ks) * 512]); }

#define MFMA4(ks)                                                                            \
    acc[0][0] = __builtin_amdgcn_mfma_f32_32x32x16_bf16(av[0][ks], bv[0][ks], acc[0][0], 0, 0, 0); \
    acc[0][1] = __builtin_amdgcn_mfma_f32_32x32x16_bf16(av[0][ks], bv[1][ks], acc[0][1], 0, 0, 0); \
    acc[1][0] = __builtin_amdgcn_mfma_f32_32x32x16_bf16(av[1][ks], bv[0][ks], acc[1][0], 0, 0, 0); \
    acc[1][1] = __builtin_amdgcn_mfma_f32_32x32x16_bf16(av[1][ks], bv[1][ks], acc[1][1], 0, 0, 0);

#define CPIN { __builtin_amdgcn_sched_group_barrier(0x100, 4, 0);                            \
               __builtin_amdgcn_sched_group_barrier(0x008, 4, 0); }

#define CTILE(bufsel) {                                                                      \
    const unsigned short* As_ = &sm[(bufsel) * 16384];                                       \
    const unsigned short* Bs_ = &sm[32768 + (bufsel) * 8192];                                \
    READ4(As_, Bs_, 0)                                                                       \
    READ4(As_, Bs_, 1) MFMA4(0) CPIN                                                         \
    READ4(As_, Bs_, 2) MFMA4(1) CPIN                                                         \
    READ4(As_, Bs_, 3) MFMA4(2) CPIN                                                         \
    MFMA4(3) __builtin_amdgcn_sched_group_barrier(0x008, 4, 0); }

#define CBAR { __builtin_amdgcn_sched_barrier(0); __builtin_amdgcn_s_barrier();              \
               __builtin_amdgcn_sched_barrier(0); }

    CBAR                                   // prologue: wait for producer's tile-0 fill
    for (int kt = 0; kt < 126; kt += 2) {
      CTILE(0) CBAR
      CTILE(1) CBAR
    }
    CTILE(0) CBAR                          // tile 126
    CTILE(1)                               // tile 127 (no barrier after)
#undef CTILE
#undef CPIN
#undef READ4

    // epilogue: 32x32 C/D layout col = lane&31, row = (reg&3) + 8*(reg>>2) + 4*(lane>>5)
    #pragma unroll
    for (int ni = 0; ni < 2; ++ni) {
      const int col  = n0 + wn * 64 + ni * 32 + l31;
      const float bc = bias[col];
      #pragma unroll
      for (int mi = 0; mi < 2; ++mi) {
        const int rbase = m0 + wm * 64 + mi * 32 + 4 * half;
        #pragma unroll
        for (int r = 0; r < 16; ++r) {
          const int row = rbase + (r & 3) + 8 * (r >> 2);
          C[(size_t)row * N_DIM + col] = acc[mi][ni][r] + bc;
        }
      }
    }
#undef MFMA4
#undef CBAR
  } else {
    // ================= PRODUCER: 4 waves, lane pr owns A-row pr =================
    const int pr = tid - 512;             // 0..255
    const float* xrow = x + (size_t)(m0 + pr) * I_DIM;
    const unsigned short* BtSlab = Bt2 + (size_t)nt * 1048576;
    const int awbase = (pr >> 5) * 2048 + (pr & 31) * 8;  // fragment-major A write base
    const int prw8   = pr * 8;                            // B-stage lane offset (shorts)

#define STAGEB(bufsel, kt1) {                                                                \
    _Pragma("unroll")                                                                        \
    for (int q = 0; q < 4; ++q) {                                                            \
      __builtin_amdgcn_global_load_lds(                                                      \
        (const __attribute__((address_space(1))) void*)(BtSlab + (size_t)(kt1) * 8192 + q * 2048 + prw8), \
        (__attribute__((address_space(3))) void*)&sm[32768 + (bufsel) * 8192 + q * 2048 + prw8], 16, 0, 0); \
    } }

#define BASIS8(bufsel, f0, f1) {                                                             \
    const float tin[8] = {(f0).x, (f0).y, (f0).z, (f0).w, (f1).x, (f1).y, (f1).z, (f1).w};   \
    _Pragma("unroll")                                                                        \
    for (int s = 0; s < 8; ++s) {                                                            \
      float t = fast_tanh(tin[s]);                                                           \
      t = fminf(fmaxf(t, -0.999f), 0.999f);                                                  \
      const float t2 = t + t;                                                                \
      const float T1 = t;                                                                    \
      const float T2 = t2 * t - 1.0f;                                                        \
      const float T3 = t2 * T2 - T1;                                                         \
      const float T4 = t2 * T3 - T2;                                                         \
      const float T5 = t2 * T4 - T3;                                                         \
      const float T6 = t2 * T5 - T4;                                                         \
      const float T7 = t2 * T6 - T5;                                                         \
      const float T8 = t2 * T7 - T6;                                                         \
      uint4 u;                                                                               \
      u.x = pk_bf16(T1, T2); u.y = pk_bf16(T3, T4);                                          \
      u.z = pk_bf16(T5, T6); u.w = pk_bf16(T7, T8);                                          \
      *reinterpret_cast<uint4*>(&sm[(bufsel) * 16384 + awbase + s * 256]) = u;               \
    } }

    float4 xE0, xE1, xO0, xO1;
    xE0 = *reinterpret_cast<const float4*>(xrow + 0);
    xE1 = *reinterpret_cast<const float4*>(xrow + 4);      // x(0)
    xO0 = *reinterpret_cast<const float4*>(xrow + 8);
    xO1 = *reinterpret_cast<const float4*>(xrow + 12);     // x(1)
    STAGEB(0, 0)
    BASIS8(0, xE0, xE1)
    __builtin_amdgcn_sched_barrier(0);
    asm volatile("s_waitcnt vmcnt(0) lgkmcnt(0)" ::: "memory");
    __builtin_amdgcn_s_barrier();
    __builtin_amdgcn_sched_barrier(0);

// tile kt_: stage B(kt_+1) + basis(kt_+1) from XU -> buf (kt_+1)&1; load x(kt_+2) into XL.
// pre-barrier vmcnt(2) leaves only the 2 x-loads in flight (sched_barrier pins the order).
#define PTILE(kt_, XU0, XU1, XL0, XL1, LX) {                                                 \
    STAGEB(((kt_) + 1) & 1, (kt_) + 1)                                                       \
    __builtin_amdgcn_sched_barrier(0);                                                       \
    BASIS8(((kt_) + 1) & 1, XU0, XU1)                                                        \
    __builtin_amdgcn_sched_barrier(0);                                                       \
    if (LX) {                                                                                \
      XL0 = *reinterpret_cast<const float4*>(xrow + ((kt_) + 2) * 8);                        \
      XL1 = *reinterpret_cast<const float4*>(xrow + ((kt_) + 2) * 8 + 4);                    \
    }                                                                                        \
    __builtin_amdgcn_sched_barrier(0);                                                       \
    if (LX) { asm volatile("s_waitcnt vmcnt(2) lgkmcnt(0)" ::: "memory"); }                  \
    else    { asm volatile("s_waitcnt vmcnt(0) lgkmcnt(0)" ::: "memory"); }                  \
    __builtin_amdgcn_s_barrier();                                                            \
    __builtin_amdgcn_sched_barrier(0); }

    for (int kt = 0; kt < 126; kt += 2) {
      PTILE(kt,     xO0, xO1, xE0, xE1, 1)   // uses x(kt+1) [odd], loads x(kt+2) [even]
      PTILE(kt + 1, xE0, xE1, xO0, xO1, 1)   // uses x(kt+2) [even], loads x(kt+3) [odd]
    }
    PTILE(126, xO0, xO1, xE0, xE1, 0)        // basis(127) from x(127); nothing left to load
    // tile 127: no producer work, no barrier
#undef PTILE
#undef BASIS8
#undef STAGEB
  }
}

extern "C" void kernel_launch(void* const* d_in, const int* in_sizes, int n_in,
                              void* d_out, int out_size, void* d_ws, size_t ws_size,
                              hipStream_t stream) {
  const float* x      = (const float*)d_in[0];
  const float* coeffs = (const float*)d_in[1];
  float* y            = (float*)d_out;

  const size_t bt_bytes = (size_t)N_DIM * K_DIM * sizeof(unsigned short); // 16.78 MB
  unsigned short* Bt2 = (unsigned short*)d_ws;
  float* bias         = (float*)((char*)d_ws + bt_bytes);

  // bias accumulator must start at zero (ws is poisoned 0xAA each call)
  hipMemsetAsync(bias, 0, N_DIM * sizeof(float), stream);

  // 96 KB dynamic LDS (double-buffered fragment-major A+B)
  hipFuncSetAttribute((const void*)gemm_kernel,
                      hipFuncAttributeMaxDynamicSharedMemorySize, 98304);

  repack_kernel<<<dim3(I_DIM / 32, N_DIM / 64), 256, 0, stream>>>(coeffs, Bt2, bias);
  gemm_kernel<<<(B_ROWS / BM) * (N_DIM / BN), 768, 98304, stream>>>(x, Bt2, bias, y);
}